// Round 12
// baseline (233.016 us; speedup 1.0000x reference)
//
#include <hip/hip_runtime.h>
#include <hip/hip_fp16.h>
#include <math.h>

#define T_SEQ 1152

typedef _Float16 f16x8 __attribute__((ext_vector_type(8)));
typedef float f32x4 __attribute__((ext_vector_type(4)));
typedef int   i32x2 __attribute__((ext_vector_type(2)));

// pair-sum over lanes (l, l^32) — guaranteed-correct shfl path.
__device__ __forceinline__ float pairsum32(float v) {
  return v + __shfl_xor(v, 32, 64);
}

// ---------------------------------------------------------------------------
// Kernel 0: M[b,m,s] = sum_n spatial_w[n,s] * L_norm[b,n,m]  ([b][m][s] layout)
// ---------------------------------------------------------------------------
__global__ void mKernel(const float* __restrict__ L, const float* __restrict__ sw,
                        float* __restrict__ Mbuf) {
  int b = blockIdx.x, tid = threadIdx.x;   // 256 threads
  int s = tid >> 6, m = tid & 63;
  float a = 0.f;
  #pragma unroll 4
  for (int n = 0; n < 64; ++n)
    a = fmaf(sw[n * 4 + s], L[(b * 64 + n) * 64 + m], a);
  Mbuf[b * 256 + m * 4 + s] = a;
}

// ---------------------------------------------------------------------------
// Kernel A v12: conv(32x1,8->8,SAME) + LN(8) + ReLU + projection -> snn.
// = v11 structure (single-wave blocks, zero barriers, 32-t tiles, 64-stage
// pipeline) with the LN pair-sum done via __shfl_xor(32) instead of the
// unverified permlane32_swap builtin (R11's only untested primitive).
// A-row remap: rows 0-3=f0-3@t, 4-7=f0-3@t+16, 8-11=f4-7@t, 12-15=f4-7@t+16
// so the LN f-partner is lane^32.
// ---------------------------------------------------------------------------
__global__ __launch_bounds__(64, 4)
void convKernel(const float* __restrict__ X, const float* __restrict__ Kw,
                const float* __restrict__ lnS, const float* __restrict__ lnB,
                const float* __restrict__ Mbuf, float* __restrict__ snn) {
  __shared__ int4 XS[8 * 68];          // [slot][row] fp16x8 rows, 8704 B

  const int bid   = blockIdx.x;        // 0..2303
  const int b     = bid / 36;
  const int tile  = bid - b * 36;      // 0..35
  const int tBase = tile * 32;
  const int lane  = threadIdx.x;       // 0..63
  const int tcol  = lane & 15;
  const int rg    = lane >> 4;         // 0..3

  // ---- A-frags (K), rows: 0-3=f0-3@0, 4-7=f0-3@16, 8-11=f4-7@0, 12-15=f4-7@16
  const int rA = lane & 15;
  const int fr = ((rA >> 3) << 2) | (rA & 3);   // f of this A row
  const int sh = ((rA >> 2) & 1) << 4;          // kh shift (0 or 16)
  f16x8 ka[12];
  #pragma unroll
  for (int q = 0; q < 12; ++q) {
    const int khs = 4 * q + rg - sh;
    #pragma unroll
    for (int j = 0; j < 8; ++j) {
      float kv = (khs >= 0 && khs < 32) ? Kw[khs * 64 + j * 8 + fr] : 0.f;
      ka[q][j] = (_Float16)kv;
    }
  }

  // ---- LN params for this lane's f-quad (fb = 0 or 4)
  const int fb = (rg >> 1) << 2;
  const float4 lnSq = *(const float4*)(lnS + fb);
  const float4 lnBq = *(const float4*)(lnB + fb);

  // ---- load geometry: 2 loads/lane/stage: (row0, half), (row1=row0+32, half)
  const int half = lane & 1;
  const int row0 = lane >> 1;          // 0..31
  const int row1 = row0 + 32;          // 32..63
  const int tg0 = tBase - 15 + row0;
  const int tg1 = tBase - 15 + row1;
  const bool v0 = (tg0 >= 0) && (tg0 < T_SEQ);
  const bool v1 = (tg1 >= 0) && (tg1 < T_SEQ);
  const float* xb = X + (size_t)b * T_SEQ * 512 + half * 4;
  const long a0 = (long)tg0 * 512;
  const long a1 = (long)tg1 * 512;
  const size_t lds0 = (size_t)row0 * 16 + half * 8;
  const size_t lds1 = (size_t)row1 * 16 + half * 8;
  char* xsb = (char*)&XS[0];

  float pacc[4][4];
  #pragma unroll
  for (int r = 0; r < 4; ++r)
    #pragma unroll
    for (int s = 0; s < 4; ++s) pacc[r][s] = 0.f;

  const float4 z4 = make_float4(0.f, 0.f, 0.f, 0.f);
  float4 pA0, pA1, pB0, pB1;

#define ISSUE(CH, P0, P1)                                                  \
  { P0 = v0 ? *(const float4*)(xb + a0 + (CH) * 8) : z4;                   \
    P1 = v1 ? *(const float4*)(xb + a1 + (CH) * 8) : z4; }

#define WRITE(CH, P0, P1)                                                  \
  { const int slot_ = (CH) & 7;                                            \
    i32x2 c0, c1;                                                          \
    c0.x = (int)__builtin_bit_cast(unsigned, __float22half2_rn(make_float2(P0.x, P0.y))); \
    c0.y = (int)__builtin_bit_cast(unsigned, __float22half2_rn(make_float2(P0.z, P0.w))); \
    c1.x = (int)__builtin_bit_cast(unsigned, __float22half2_rn(make_float2(P1.x, P1.y))); \
    c1.y = (int)__builtin_bit_cast(unsigned, __float22half2_rn(make_float2(P1.z, P1.w))); \
    *(i32x2*)(xsb + slot_ * 1088 + lds0) = c0;                             \
    *(i32x2*)(xsb + slot_ * 1088 + lds1) = c1; }

#define COMPUTE(CH)                                                        \
  { const int slot_ = (CH) & 7;                                            \
    f32x4 acc = {0.f, 0.f, 0.f, 0.f};                                      \
    const int4* rb = XS + slot_ * 68 + tcol + rg;                          \
    _Pragma("unroll")                                                      \
    for (int q = 0; q < 12; ++q) {                                         \
      f16x8 xf = __builtin_bit_cast(f16x8, rb[4 * q]);                     \
      acc = __builtin_amdgcn_mfma_f32_16x16x32_f16(ka[q], xf, acc, 0, 0, 0); \
    }                                                                      \
    float s1 = (acc[0] + acc[1]) + (acc[2] + acc[3]);                      \
    float s2 = fmaf(acc[0], acc[0], fmaf(acc[1], acc[1],                   \
               fmaf(acc[2], acc[2], acc[3] * acc[3])));                    \
    s1 = pairsum32(s1);                                                    \
    s2 = pairsum32(s2);                                                    \
    float mu = s1 * 0.125f;                                                \
    float var = fmaf(-mu, mu, s2 * 0.125f);                                \
    float rs = 1.0f / sqrtf(var + 1e-6f);                                  \
    const float4 Mc = *(const float4*)(Mbuf + b * 256 + (CH) * 4);         \
    const float lnSa[4] = {lnSq.x, lnSq.y, lnSq.z, lnSq.w};                \
    const float lnBa[4] = {lnBq.x, lnBq.y, lnBq.z, lnBq.w};                \
    _Pragma("unroll")                                                      \
    for (int r = 0; r < 4; ++r) {                                          \
      float hr = fmaxf(fmaf((acc[r] - mu) * rs, lnSa[r], lnBa[r]), 0.f);   \
      pacc[r][0] = fmaf(hr, Mc.x, pacc[r][0]);                             \
      pacc[r][1] = fmaf(hr, Mc.y, pacc[r][1]);                             \
      pacc[r][2] = fmaf(hr, Mc.z, pacc[r][2]);                             \
      pacc[r][3] = fmaf(hr, Mc.w, pacc[r][3]);                             \
    } }

  // ---- prologue: fill pipeline (loads 4 ahead, writes 2 ahead)
  ISSUE(0, pA0, pA1);
  ISSUE(1, pB0, pB1);
  WRITE(0, pA0, pA1);
  ISSUE(2, pA0, pA1);
  WRITE(1, pB0, pB1);
  ISSUE(3, pB0, pB1);

  #pragma unroll 1
  for (int s = 0; s < 64; s += 2) {
    if (s + 2 < 64) WRITE(s + 2, pA0, pA1);
    if (s + 4 < 64) ISSUE(s + 4, pA0, pA1);
    COMPUTE(s);
    if (s + 3 < 64) WRITE(s + 3, pB0, pB1);
    if (s + 5 < 64) ISSUE(s + 5, pB0, pB1);
    COMPUTE(s + 1);
  }
#undef ISSUE
#undef WRITE
#undef COMPUTE

  // ---- store: lane owns (t = tcol + (rg&1)*16, f-quad fb..fb+3), all 4 s
  {
    const int tloc = tcol + (rg & 1) * 16;
    float* op = snn + ((size_t)b * T_SEQ + tBase + tloc) * 32;
    #pragma unroll
    for (int s = 0; s < 4; ++s)
      *(float4*)(op + s * 8 + fb) =
          make_float4(pacc[0][s], pacc[1][s], pacc[2][s], pacc[3][s]);
  }
}

// ---------------------------------------------------------------------------
// Kernel B: LIF scan — 1 chain/thread (32 blocks x 64 thr = 2048 chains),
// 24-deep ping-pong prefetch.
// ---------------------------------------------------------------------------
__global__ __launch_bounds__(64, 1)
void scanKernel(const float* __restrict__ snn, float* __restrict__ flat,
                float* __restrict__ spkPart) {
  const int tid = threadIdx.x;        // 0..63
  const int j = tid & 31;
  const int b = blockIdx.x * 2 + (tid >> 5);
  const float* base = snn + (size_t)b * T_SEQ * 32 + j;

  float m1 = 0.f, m2 = 0.f, mo = 0.f, s1 = 0.f, s2 = 0.f;
  float cur[24], nxt[24];
  #pragma unroll
  for (int u = 0; u < 24; ++u) cur[u] = base[(size_t)u * 32];

  #pragma unroll 1
  for (int ch = 0; ch < 48; ++ch) {
    if (ch < 47) {
      #pragma unroll
      for (int u = 0; u < 24; ++u) nxt[u] = base[(size_t)((ch + 1) * 24 + u) * 32];
    }
    float aS = 0.f, aE = 0.f;
    #pragma unroll
    for (int u = 0; u < 24; ++u) {
      m1 = m1 * 0.8f + cur[u];
      float sp1 = (m1 > 0.5f) ? 1.f : 0.f;  m1 -= sp1 * 0.5f;
      m2 = m2 * 0.9f + sp1;
      float sp2 = (m2 > 0.5f) ? 1.f : 0.f;  m2 -= sp2 * 0.5f;
      mo = mo * 0.95f + sp2;
      s1 += sp1; s2 += sp2;
      if (u < 12) aS += mo; else aE += mo;
    }
    flat[b * 3072 + ch * 64 + j]      = aS / 12.0f;
    flat[b * 3072 + ch * 64 + 32 + j] = aE / 12.0f;
    if (ch < 47) {
      #pragma unroll
      for (int u = 0; u < 24; ++u) cur[u] = nxt[u];
    }
  }
  for (int off = 16; off > 0; off >>= 1) {
    s1 += __shfl_down(s1, off, 32);
    s2 += __shfl_down(s2, off, 32);
  }
  if (j == 0) { spkPart[b * 2] = s1; spkPart[b * 2 + 1] = s2; }
}

// ---------------------------------------------------------------------------
// Kernel C: y = gelu(flat @ W1 + b1); logits = y @ W2 + b2 ; firing rate.
// ---------------------------------------------------------------------------
__global__ void mlpKernel(const float* __restrict__ flat, const float* __restrict__ W1,
                          const float* __restrict__ b1, const float* __restrict__ W2,
                          const float* __restrict__ b2, const float* __restrict__ spkPart,
                          float* __restrict__ out) {
  if (blockIdx.x == 64) {
    if (threadIdx.x == 0) {
      float s1 = 0.f, s2 = 0.f;
      for (int i = 0; i < 64; ++i) { s1 += spkPart[2*i]; s2 += spkPart[2*i+1]; }
      out[256] = (s1 + s2) * 0.5f / (64.0f * 1152.0f * 32.0f);
    }
    return;
  }
  const int b = blockIdx.x;
  const int tid = threadIdx.x;        // 256
  const int u = tid & 31, kc = tid >> 5;
  __shared__ float red[256];
  __shared__ float ys[32];
  float p = 0.f;
  const int kbeg = kc * 384, kend = kbeg + 384;
  #pragma unroll 4
  for (int k = kbeg; k < kend; ++k)
    p = fmaf(flat[b*3072 + k], W1[k*32 + u], p);
  red[tid] = p;
  __syncthreads();
  if (kc == 0) {
    float y = b1[u];
    #pragma unroll
    for (int q = 0; q < 8; ++q) y += red[q*32 + u];
    float y3 = y * y * y;
    float th = tanhf(0.7978845608028654f * (y + 0.044715f * y3));
    ys[u] = 0.5f * y * (1.0f + th);
  }
  __syncthreads();
  if (tid < 4) {
    float accv = b2[tid];
    #pragma unroll
    for (int q = 0; q < 32; ++q) accv = fmaf(ys[q], W2[q*4 + tid], accv);
    out[b*4 + tid] = accv;
  }
}

// ---------------------------------------------------------------------------
extern "C" void kernel_launch(void* const* d_in, const int* in_sizes, int n_in,
                              void* d_out, int out_size, void* d_ws, size_t ws_size,
                              hipStream_t stream) {
  const float* L   = (const float*)d_in[0];
  const float* X   = (const float*)d_in[1];
  // d_in[2] = deterministic (unused)
  const float* Kw  = (const float*)d_in[3];
  const float* lnS = (const float*)d_in[4];
  const float* lnB = (const float*)d_in[5];
  const float* sw  = (const float*)d_in[6];
  const float* W1  = (const float*)d_in[7];
  const float* b1  = (const float*)d_in[8];
  const float* W2  = (const float*)d_in[9];
  const float* b2  = (const float*)d_in[10];

  float* ws   = (float*)d_ws;
  float* Mbuf = ws;                       // 64*4*64    = 16384
  float* snn  = Mbuf + 16384;             // 64*1152*32 = 2359296
  float* flat = snn + 2359296;            // 64*3072    = 196608
  float* spk  = flat + 196608;            // 128
  float* out  = (float*)d_out;

  mKernel<<<64, 256, 0, stream>>>(L, sw, Mbuf);
  convKernel<<<2304, 64, 0, stream>>>(X, Kw, lnS, lnB, Mbuf, snn);
  scanKernel<<<32, 64, 0, stream>>>(snn, flat, spk);
  mlpKernel<<<65, 256, 0, stream>>>(flat, W1, b1, W2, b2, spk, out);
}

// Round 13
// 147.779 us; speedup vs baseline: 1.5768x; 1.5768x over previous
//
#include <hip/hip_runtime.h>
#include <hip/hip_fp16.h>
#include <math.h>

#define T_SEQ 1152

typedef _Float16 f16x8 __attribute__((ext_vector_type(8)));
typedef float f32x4 __attribute__((ext_vector_type(4)));

// ---------------------------------------------------------------------------
// Kernel 0: M[b,m,s] = sum_n spatial_w[n,s] * L_norm[b,n,m]  ([b][m][s] layout)
// ---------------------------------------------------------------------------
__global__ void mKernel(const float* __restrict__ L, const float* __restrict__ sw,
                        float* __restrict__ Mbuf) {
  int b = blockIdx.x, tid = threadIdx.x;   // 256 threads
  int s = tid >> 6, m = tid & 63;
  float a = 0.f;
  #pragma unroll 4
  for (int n = 0; n < 64; ++n)
    a = fmaf(sw[n * 4 + s], L[(b * 64 + n) * 64 + m], a);
  Mbuf[b * 256 + m * 4 + s] = a;
}

// ---------------------------------------------------------------------------
// Kernel A v13 = R7 skeleton + v8-verified dual-shift GEMM + float4 hT.
// conv(32x1,8->8,SAME) + LN(8) + ReLU + projection -> snn[b,t,32].
// GEMM: A = K (16 rows = 8f x {t, t+16} kh-shift), B = X (16 cols = t),
// K-dim = 384 (12 MFMA of K=32). Block 256 thr = 4 waves (h = t-half of the
// 64-t tile, g = c-half); 8 c-parts of 8 channels; XS staged to LDS with the
// R7 2-barrier-per-part discipline; acc -> wave-private hT (float4 tiles,
// conflict-free) -> per-thread LN + proj (NO cross-lane op per channel).
// Epilogue: shfl_xor(1) cslot merge + RedF (stride-33) cross-g merge.
// ---------------------------------------------------------------------------
__global__ __launch_bounds__(256, 4)
void convKernel(const float* __restrict__ X, const float* __restrict__ Kw,
                const float* __restrict__ lnS, const float* __restrict__ lnB,
                const float* __restrict__ Mbuf, float* __restrict__ snn) {
  __shared__ int4   XS[8 * 97];       // [c2][tl] fp16x8 rows; 12416 B; RedF alias
  __shared__ float4 hT4[1024];        // [wid][c2l][fq][tloc] ; 16384 B

  const int bid  = blockIdx.x;        // 0..1151
  const int b    = bid / 18;
  const int tile = bid - b * 18;      // 0..17
  const int t0   = tile * 64;
  const int tid  = threadIdx.x;       // 0..255
  const int lane = tid & 63;
  const int wid  = tid >> 6;          // 0..3
  const int h    = wid & 1;           // t-half (0: t0.., 1: t0+32..)
  const int g    = wid >> 1;          // c-half (c2 = g*4 + cc)
  const int w32  = h * 32;
  const int tcol = lane & 15;         // B col = local t
  const int rg   = lane >> 4;         // k-group; C/D rows rg*4+r
  const int fq   = rg & 1;            // f-quad of this lane's C/D rows
  const int tloc = tcol + ((rg >> 1) << 4);   // C/D local t (0..31)

  // ---- A-frags (K): rows 0-7 = f0-7 @ t, rows 8-15 = f0-7 @ t+16
  const int rA = lane & 15;
  const int fr = rA & 7;
  const int sh16 = (rA >> 3) << 4;
  f16x8 ka[12];
  #pragma unroll
  for (int q = 0; q < 12; ++q) {
    const int khs = 4 * q + rg - sh16;
    #pragma unroll
    for (int j = 0; j < 8; ++j) {
      float kv = (khs >= 0 && khs < 32) ? Kw[khs * 64 + j * 8 + fr] : 0.f;
      ka[q][j] = (_Float16)kv;
    }
  }

  // ---- per-thread LN/proj ids: 2 points (t, c2l) per part
  const int tpt   = lane >> 1;        // local t 0..31
  const int cslot = lane & 1;         // c2l pair {cslot*2, cslot*2+1}

  // ---- staging geometry (R7-verified): 760 rows = 8 c2 x 95 tl
  const int sc2 = tid & 7;
  int stl[3]; long gb[3]; bool tv[3];
  #pragma unroll
  for (int k = 0; k < 3; ++k) {
    stl[k] = (tid >> 3) + 32 * k;
    int tt = t0 - 15 + stl[k];
    tv[k] = (stl[k] < 95) && (tt >= 0) && (tt < T_SEQ);
    gb[k] = (long)tt * 512 + sc2 * 8;
  }
  const float* xb = X + (size_t)(b * T_SEQ) * 512;

  float pacc[4][8];
  #pragma unroll
  for (int s = 0; s < 4; ++s)
    #pragma unroll
    for (int f = 0; f < 8; ++f) pacc[s][f] = 0.f;

  #pragma unroll 1
  for (int part = 0; part < 8; ++part) {
    // ---- stage X rows -> fp16 XS (direct, R7 style)
    #pragma unroll
    for (int k = 0; k < 3; ++k) {
      if (stl[k] < 95) {
        float4 a0 = make_float4(0.f, 0.f, 0.f, 0.f), a1 = a0;
        if (tv[k]) {
          const float* p = xb + gb[k] + part * 64;
          a0 = *(const float4*)p;
          a1 = *(const float4*)(p + 4);
        }
        unsigned u0 = __builtin_bit_cast(unsigned, __float22half2_rn(make_float2(a0.x, a0.y)));
        unsigned u1 = __builtin_bit_cast(unsigned, __float22half2_rn(make_float2(a0.z, a0.w)));
        unsigned u2 = __builtin_bit_cast(unsigned, __float22half2_rn(make_float2(a1.x, a1.y)));
        unsigned u3 = __builtin_bit_cast(unsigned, __float22half2_rn(make_float2(a1.z, a1.w)));
        int4 v; v.x = (int)u0; v.y = (int)u1; v.z = (int)u2; v.w = (int)u3;
        XS[sc2 * 97 + stl[k]] = v;
      }
    }
    __syncthreads();   // B1: XS ready

    // ---- MFMA: this wave's 4 c2; acc -> hT4 (wave-private, conflict-free)
    #pragma unroll 2
    for (int cc = 0; cc < 4; ++cc) {
      f32x4 acc = {0.f, 0.f, 0.f, 0.f};
      const int rb = (g * 4 + cc) * 97 + w32 + tcol + rg;
      #pragma unroll
      for (int q = 0; q < 12; ++q) {
        f16x8 xf = __builtin_bit_cast(f16x8, XS[rb + 4 * q]);
        acc = __builtin_amdgcn_mfma_f32_16x16x32_f16(ka[q], xf, acc, 0, 0, 0);
      }
      float4 st; st.x = acc[0]; st.y = acc[1]; st.z = acc[2]; st.w = acc[3];
      hT4[wid * 256 + cc * 64 + fq * 32 + tloc] = st;
    }
    // wave-local lgkmcnt orders hT writes vs reads below (compiler-inserted)

    // ---- per-thread LN + ReLU + proj: 2 points (tpt, c2l)
    #pragma unroll
    for (int cc2 = 0; cc2 < 2; ++cc2) {
      const int c2l = cslot * 2 + cc2;
      float4 lo = hT4[wid * 256 + c2l * 64 + tpt];
      float4 hi = hT4[wid * 256 + c2l * 64 + 32 + tpt];
      float hv[8] = { lo.x, lo.y, lo.z, lo.w, hi.x, hi.y, hi.z, hi.w };
      float mu = 0.f;
      #pragma unroll
      for (int f = 0; f < 8; ++f) mu += hv[f];
      mu *= 0.125f;
      float var = 0.f;
      #pragma unroll
      for (int f = 0; f < 8; ++f) { float d = hv[f] - mu; hv[f] = d; var = fmaf(d, d, var); }
      float rs = 1.0f / sqrtf(var * 0.125f + 1e-6f);
      const int c = part * 8 + g * 4 + c2l;
      const float4 Mc = *(const float4*)(Mbuf + b * 256 + c * 4);
      #pragma unroll
      for (int f = 0; f < 8; ++f) {
        float hh = fmaxf(fmaf(hv[f] * rs, lnS[f], lnB[f]), 0.f);
        pacc[0][f] = fmaf(hh, Mc.x, pacc[0][f]);
        pacc[1][f] = fmaf(hh, Mc.y, pacc[1][f]);
        pacc[2][f] = fmaf(hh, Mc.z, pacc[2][f]);
        pacc[3][f] = fmaf(hh, Mc.w, pacc[3][f]);
      }
    }
    __syncthreads();   // B2: all XS reads done before next part's staging
  }

  // ---- epilogue: cslot merge (once) + cross-g merge via RedF (stride 33)
  #pragma unroll
  for (int s = 0; s < 4; ++s)
    #pragma unroll
    for (int f = 0; f < 8; ++f)
      pacc[s][f] += __shfl_xor(pacc[s][f], 1, 64);

  float* RedF = (float*)&XS[0];       // 64*33 = 2112 floats = 8448 B, aliases XS
  const int trow = h * 32 + tpt;
  if (g == 0 && cslot == 0) {
    #pragma unroll
    for (int s = 0; s < 4; ++s)
      #pragma unroll
      for (int f = 0; f < 8; ++f)
        RedF[trow * 33 + s * 8 + f] = pacc[s][f];
  }
  __syncthreads();
  if (g == 1 && cslot == 0) {
    float* op = snn + ((size_t)b * T_SEQ + t0 + trow) * 32;
    #pragma unroll
    for (int s = 0; s < 4; ++s) {
      float4 v0, v1;
      v0.x = pacc[s][0] + RedF[trow * 33 + s * 8 + 0];
      v0.y = pacc[s][1] + RedF[trow * 33 + s * 8 + 1];
      v0.z = pacc[s][2] + RedF[trow * 33 + s * 8 + 2];
      v0.w = pacc[s][3] + RedF[trow * 33 + s * 8 + 3];
      v1.x = pacc[s][4] + RedF[trow * 33 + s * 8 + 4];
      v1.y = pacc[s][5] + RedF[trow * 33 + s * 8 + 5];
      v1.z = pacc[s][6] + RedF[trow * 33 + s * 8 + 6];
      v1.w = pacc[s][7] + RedF[trow * 33 + s * 8 + 7];
      *(float4*)(op + s * 8)     = v0;
      *(float4*)(op + s * 8 + 4) = v1;
    }
  }
}

// ---------------------------------------------------------------------------
// Kernel B: LIF scan — 1 chain/thread (32 blocks x 64 thr = 2048 chains),
// 24-deep ping-pong prefetch.
// ---------------------------------------------------------------------------
__global__ __launch_bounds__(64, 1)
void scanKernel(const float* __restrict__ snn, float* __restrict__ flat,
                float* __restrict__ spkPart) {
  const int tid = threadIdx.x;        // 0..63
  const int j = tid & 31;
  const int b = blockIdx.x * 2 + (tid >> 5);
  const float* base = snn + (size_t)b * T_SEQ * 32 + j;

  float m1 = 0.f, m2 = 0.f, mo = 0.f, s1 = 0.f, s2 = 0.f;
  float cur[24], nxt[24];
  #pragma unroll
  for (int u = 0; u < 24; ++u) cur[u] = base[(size_t)u * 32];

  #pragma unroll 1
  for (int ch = 0; ch < 48; ++ch) {
    if (ch < 47) {
      #pragma unroll
      for (int u = 0; u < 24; ++u) nxt[u] = base[(size_t)((ch + 1) * 24 + u) * 32];
    }
    float aS = 0.f, aE = 0.f;
    #pragma unroll
    for (int u = 0; u < 24; ++u) {
      m1 = m1 * 0.8f + cur[u];
      float sp1 = (m1 > 0.5f) ? 1.f : 0.f;  m1 -= sp1 * 0.5f;
      m2 = m2 * 0.9f + sp1;
      float sp2 = (m2 > 0.5f) ? 1.f : 0.f;  m2 -= sp2 * 0.5f;
      mo = mo * 0.95f + sp2;
      s1 += sp1; s2 += sp2;
      if (u < 12) aS += mo; else aE += mo;
    }
    flat[b * 3072 + ch * 64 + j]      = aS / 12.0f;
    flat[b * 3072 + ch * 64 + 32 + j] = aE / 12.0f;
    if (ch < 47) {
      #pragma unroll
      for (int u = 0; u < 24; ++u) cur[u] = nxt[u];
    }
  }
  for (int off = 16; off > 0; off >>= 1) {
    s1 += __shfl_down(s1, off, 32);
    s2 += __shfl_down(s2, off, 32);
  }
  if (j == 0) { spkPart[b * 2] = s1; spkPart[b * 2 + 1] = s2; }
}

// ---------------------------------------------------------------------------
// Kernel C: y = gelu(flat @ W1 + b1); logits = y @ W2 + b2 ; firing rate.
// ---------------------------------------------------------------------------
__global__ void mlpKernel(const float* __restrict__ flat, const float* __restrict__ W1,
                          const float* __restrict__ b1, const float* __restrict__ W2,
                          const float* __restrict__ b2, const float* __restrict__ spkPart,
                          float* __restrict__ out) {
  if (blockIdx.x == 64) {
    if (threadIdx.x == 0) {
      float s1 = 0.f, s2 = 0.f;
      for (int i = 0; i < 64; ++i) { s1 += spkPart[2*i]; s2 += spkPart[2*i+1]; }
      out[256] = (s1 + s2) * 0.5f / (64.0f * 1152.0f * 32.0f);
    }
    return;
  }
  const int b = blockIdx.x;
  const int tid = threadIdx.x;        // 256
  const int u = tid & 31, kc = tid >> 5;
  __shared__ float red[256];
  __shared__ float ys[32];
  float p = 0.f;
  const int kbeg = kc * 384, kend = kbeg + 384;
  #pragma unroll 4
  for (int k = kbeg; k < kend; ++k)
    p = fmaf(flat[b*3072 + k], W1[k*32 + u], p);
  red[tid] = p;
  __syncthreads();
  if (kc == 0) {
    float y = b1[u];
    #pragma unroll
    for (int q = 0; q < 8; ++q) y += red[q*32 + u];
    float y3 = y * y * y;
    float th = tanhf(0.7978845608028654f * (y + 0.044715f * y3));
    ys[u] = 0.5f * y * (1.0f + th);
  }
  __syncthreads();
  if (tid < 4) {
    float accv = b2[tid];
    #pragma unroll
    for (int q = 0; q < 32; ++q) accv = fmaf(ys[q], W2[q*4 + tid], accv);
    out[b*4 + tid] = accv;
  }
}

// ---------------------------------------------------------------------------
extern "C" void kernel_launch(void* const* d_in, const int* in_sizes, int n_in,
                              void* d_out, int out_size, void* d_ws, size_t ws_size,
                              hipStream_t stream) {
  const float* L   = (const float*)d_in[0];
  const float* X   = (const float*)d_in[1];
  // d_in[2] = deterministic (unused)
  const float* Kw  = (const float*)d_in[3];
  const float* lnS = (const float*)d_in[4];
  const float* lnB = (const float*)d_in[5];
  const float* sw  = (const float*)d_in[6];
  const float* W1  = (const float*)d_in[7];
  const float* b1  = (const float*)d_in[8];
  const float* W2  = (const float*)d_in[9];
  const float* b2  = (const float*)d_in[10];

  float* ws   = (float*)d_ws;
  float* Mbuf = ws;                       // 64*4*64    = 16384
  float* snn  = Mbuf + 16384;             // 64*1152*32 = 2359296
  float* flat = snn + 2359296;            // 64*3072    = 196608
  float* spk  = flat + 196608;            // 128
  float* out  = (float*)d_out;

  mKernel<<<64, 256, 0, stream>>>(L, sw, Mbuf);
  convKernel<<<1152, 256, 0, stream>>>(X, Kw, lnS, lnB, Mbuf, snn);
  scanKernel<<<32, 64, 0, stream>>>(snn, flat, spk);
  mlpKernel<<<65, 256, 0, stream>>>(flat, W1, b1, W2, b2, spk, out);
}